// Round 4
// baseline (426.007 us; speedup 1.0000x reference)
//
#include <hip/hip_runtime.h>

// Problem constants (match reference)
#define T_DIM 64
#define K_DIM 8192
#define N_DIM 8192
#define KSPLIT 8
#define KC (K_DIM / KSPLIT)   // 1024 codes per K-chunk block
#define BN 128                // output channels per block
#define NBX (N_DIM / BN)      // 64 N-blocks
#define BK 64                 // int32 codes per LDS tile (256B per row)
#define NT (KC / BK)          // 16 tiles per block

typedef __fp16 half8_t __attribute__((ext_vector_type(8)));
typedef __fp16 half2_t __attribute__((ext_vector_type(2)));
typedef float  f32x4   __attribute__((ext_vector_type(4)));
typedef int    i32x4   __attribute__((ext_vector_type(4)));

// ---------------------------------------------------------------------------
// Kernel 1: x (f32) -> xh (f16); rowsum partials (f16-rounded, per quarter-row).
__global__ __launch_bounds__(256) void prep_kernel(const float* __restrict__ x,
                                                   __fp16* __restrict__ xh,
                                                   float* __restrict__ rowsum_part) {
    const int t = blockIdx.x >> 2;
    const int q = blockIdx.x & 3;
    const int kbase = q * (K_DIM / 4) + threadIdx.x * 8;
    const float* xr = x + (size_t)t * K_DIM + kbase;
    __fp16* xhr = xh + (size_t)t * K_DIM + kbase;

    f32x4 v0 = *(const f32x4*)xr;
    f32x4 v1 = *(const f32x4*)(xr + 4);
    half8_t h;
    h[0] = (__fp16)v0[0]; h[1] = (__fp16)v0[1]; h[2] = (__fp16)v0[2]; h[3] = (__fp16)v0[3];
    h[4] = (__fp16)v1[0]; h[5] = (__fp16)v1[1]; h[6] = (__fp16)v1[2]; h[7] = (__fp16)v1[3];
    *(half8_t*)xhr = h;

    float s = 0.0f;
    #pragma unroll
    for (int i = 0; i < 8; ++i) s += (float)h[i];

    #pragma unroll
    for (int off = 32; off > 0; off >>= 1) s += __shfl_down(s, off, 64);
    __shared__ float red[4];
    const int lane = threadIdx.x & 63;
    const int w = threadIdx.x >> 6;
    if (lane == 0) red[w] = s;
    __syncthreads();
    if (threadIdx.x == 0) rowsum_part[t * 4 + q] = red[0] + red[1] + red[2] + red[3];
}

// ---------------------------------------------------------------------------
// Kernel 2: partial S[t,o] = sum_{k in chunk} xh[t,k]*q[o,k] via f16 MFMA.
// B (qweight) staged global->LDS via global_load_lds (no VGPR transit),
// double-buffered, 16B-granule XOR swizzle (linear LDS dest + pre-swizzled
// global source + swizzled ds_read). Grid: (NBX, KSPLIT). 256 thr = 4 waves.
__global__ __launch_bounds__(256, 2) void woq_gemm_kernel(
        const int* __restrict__ qw, const __fp16* __restrict__ xh,
        float* __restrict__ part) {
    __shared__ int ldsB[2][128 * BK];   // 2 x 32 KB

    const int bx = blockIdx.x;        // N block (64)
    const int bz = blockIdx.y;        // K chunk (KSPLIT)
    const int tid = threadIdx.x;
    const int wid = __builtin_amdgcn_readfirstlane(tid >> 6);
    const int lane = tid & 63;
    const int r = lane & 15;          // fragment row/col index
    const int g = lane >> 4;          // k-group (0..3)

    const int n_base = bx * BN;
    const int k0 = bz * KC;

    // A frag base: token row r, k = k0 + g*8 (+ kt*64 + s*32 later)
    const __fp16* aptr = xh + (size_t)r * K_DIM + k0 + g * 8;

    f32x4 acc[4][2] = {};   // 4 m-tiles (64 tokens) x 2 n-tiles (32 channels)

    // Stage tile kt into ldsB[buf]. Wave w stages rows [w*32, w*32+32).
    // Load j covers 4 rows: lane L -> row w*32+j*4+(L>>4), 16B chunk (L&15).
    // Global column is pre-swizzled: chunk index c16 XOR (row & 15).
#define STAGE(buf, kt) do {                                                       \
        _Pragma("unroll")                                                         \
        for (int j = 0; j < 8; ++j) {                                             \
            const int row_t = wid * 32 + j * 4 + g;                               \
            const int* src = qw + (size_t)(n_base + row_t) * K_DIM + k0           \
                             + (kt) * BK + ((r ^ (row_t & 15)) << 2);             \
            int* dst = &ldsB[buf][(wid * 32 + j * 4) * BK];                       \
            __builtin_amdgcn_global_load_lds(                                     \
                (const __attribute__((address_space(1))) void*)src,               \
                (__attribute__((address_space(3))) void*)dst, 16, 0, 0);          \
        }                                                                         \
    } while (0)

    // Compute one tile (BK=64 -> two k-steps of 32) from ldsB[buf].
#define COMPUTE(buf, kt) do {                                                     \
        _Pragma("unroll")                                                         \
        for (int s = 0; s < 2; ++s) {                                             \
            half8_t af[4];                                                        \
            _Pragma("unroll")                                                     \
            for (int m = 0; m < 4; ++m)                                           \
                af[m] = *(const half8_t*)(aptr + (size_t)m * 16 * K_DIM           \
                                          + (kt) * BK + s * 32);                  \
            half8_t bf[2];                                                        \
            _Pragma("unroll")                                                     \
            for (int n = 0; n < 2; ++n) {                                         \
                const int row_t = wid * 32 + n * 16 + r;                          \
                i32x4 q0 = *(const i32x4*)&ldsB[buf][row_t * BK                   \
                                + (((s * 8 + g * 2 + 0) ^ r) << 2)];              \
                i32x4 q1 = *(const i32x4*)&ldsB[buf][row_t * BK                   \
                                + (((s * 8 + g * 2 + 1) ^ r) << 2)];              \
                union { half8_t h8; half2_t h2[4]; } u;                           \
                u.h2[0] = __builtin_amdgcn_cvt_pkrtz((float)q0[0], (float)q0[1]); \
                u.h2[1] = __builtin_amdgcn_cvt_pkrtz((float)q0[2], (float)q0[3]); \
                u.h2[2] = __builtin_amdgcn_cvt_pkrtz((float)q1[0], (float)q1[1]); \
                u.h2[3] = __builtin_amdgcn_cvt_pkrtz((float)q1[2], (float)q1[3]); \
                bf[n] = u.h8;                                                     \
            }                                                                     \
            _Pragma("unroll")                                                     \
            for (int m = 0; m < 4; ++m)                                           \
                _Pragma("unroll")                                                 \
                for (int n = 0; n < 2; ++n)                                       \
                    acc[m][n] = __builtin_amdgcn_mfma_f32_16x16x32_f16(           \
                        af[m], bf[n], acc[m][n], 0, 0, 0);                        \
        }                                                                         \
    } while (0)

    STAGE(0, 0);
    __syncthreads();                      // vmcnt drained by compiler before barrier

    for (int kt = 0; kt < NT; kt += 2) {
        if (kt + 1 < NT) STAGE(1, kt + 1);
        COMPUTE(0, kt);
        __syncthreads();
        if (kt + 2 < NT) STAGE(0, kt + 2);
        COMPUTE(1, kt + 1);
        __syncthreads();
    }

    // Store raw partials, wave-private coalesced layout:
    //   part[((bz*NBX + bx)*4 + wid)*2048 + ((n*4+m)*4+j)*64 + g*16 + r]
    float* pp = part + (((size_t)bz * NBX + bx) * 4 + wid) * 2048 + g * 16 + r;
    #pragma unroll
    for (int n = 0; n < 2; ++n)
        #pragma unroll
        for (int m = 0; m < 4; ++m)
            #pragma unroll
            for (int j = 0; j < 4; ++j)
                pp[((n * 4 + m) * 4 + j) * 64] = acc[m][n][j];
}

// ---------------------------------------------------------------------------
// Kernel 3: sum KSPLIT partials, apply scale/zero-point/bias, write out.
__global__ __launch_bounds__(256) void reduce_kernel(
        const float* __restrict__ part, const float* __restrict__ rowsum_part,
        const float* __restrict__ scales, const int* __restrict__ zps,
        const float* __restrict__ bias, float* __restrict__ out) {
    const int idx = blockIdx.x * 256 + threadIdx.x;
    const int e = idx * 4;            // flat output index
    const int t = e >> 13;            // / 8192
    const int c = e & (N_DIM - 1);
    const int bx = c >> 7;
    const int wid = (c >> 5) & 3;
    const int n = (c >> 4) & 1;
    const int r0 = c & 15;
    const int m = t >> 4;
    const int g = (t >> 2) & 3;
    const int j = t & 3;

    const size_t off = ((size_t)bx * 4 + wid) * 2048 + ((n * 4 + m) * 4 + j) * 64 + g * 16 + r0;
    f32x4 s = {0.f, 0.f, 0.f, 0.f};
    #pragma unroll
    for (int bz = 0; bz < KSPLIT; ++bz)
        s += *(const f32x4*)(part + (size_t)bz * (NBX * 4 * 2048) + off);

    const float rs = rowsum_part[t * 4 + 0] + rowsum_part[t * 4 + 1] +
                     rowsum_part[t * 4 + 2] + rowsum_part[t * 4 + 3];

    f32x4 sc = *(const f32x4*)(scales + c);
    i32x4 zp = *(const i32x4*)(zps + c);
    f32x4 bv = *(const f32x4*)(bias + c);
    f32x4 y;
    #pragma unroll
    for (int i = 0; i < 4; ++i)
        y[i] = sc[i] * (s[i] - (float)zp[i] * rs) + bv[i];
    *(f32x4*)(out + e) = y;
}

// ---------------------------------------------------------------------------
extern "C" void kernel_launch(void* const* d_in, const int* in_sizes, int n_in,
                              void* d_out, int out_size, void* d_ws, size_t ws_size,
                              hipStream_t stream) {
    const float* x      = (const float*)d_in[0];
    const int*   qw     = (const int*)d_in[1];
    const float* scales = (const float*)d_in[2];
    const int*   zps    = (const int*)d_in[3];
    const float* bias   = (const float*)d_in[4];
    float* out = (float*)d_out;

    // Workspace: xh (1 MiB @0) | rowsum_part (1 KiB @1 MiB) | partials (16 MiB @2 MiB)
    __fp16* xh          = (__fp16*)d_ws;
    float*  rowsum_part = (float*)((char*)d_ws + (1u << 20));
    float*  part        = (float*)((char*)d_ws + (2u << 20));

    prep_kernel<<<256, 256, 0, stream>>>(x, xh, rowsum_part);
    woq_gemm_kernel<<<dim3(NBX, KSPLIT), 256, 0, stream>>>(qw, xh, part);
    reduce_kernel<<<(T_DIM * N_DIM / 4) / 256, 256, 0, stream>>>(
        part, rowsum_part, scales, zps, bias, out);
}

// Round 5
// 383.294 us; speedup vs baseline: 1.1114x; 1.1114x over previous
//
#include <hip/hip_runtime.h>

// Problem constants (match reference)
#define T_DIM 64
#define K_DIM 8192
#define N_DIM 8192
#define BN 32                 // output channels per block
#define BK 256                // int32 codes per tile (1 KB per row)
#define NT (K_DIM / BK)       // 32 tiles
#define NBLK (N_DIM / BN)     // 256 blocks = 1 per CU

typedef __fp16 half8_t __attribute__((ext_vector_type(8)));
typedef __fp16 half2_t __attribute__((ext_vector_type(2)));
typedef float  f32x4   __attribute__((ext_vector_type(4)));
typedef int    i32x4   __attribute__((ext_vector_type(4)));

// ---------------------------------------------------------------------------
// Kernel 1: x (f32) -> xh (f16); rowsum partials (f16-rounded, per quarter-row).
__global__ __launch_bounds__(256) void prep_kernel(const float* __restrict__ x,
                                                   __fp16* __restrict__ xh,
                                                   float* __restrict__ rowsum_part) {
    const int t = blockIdx.x >> 2;
    const int q = blockIdx.x & 3;
    const int kbase = q * (K_DIM / 4) + threadIdx.x * 8;
    const float* xr = x + (size_t)t * K_DIM + kbase;
    __fp16* xhr = xh + (size_t)t * K_DIM + kbase;

    f32x4 v0 = *(const f32x4*)xr;
    f32x4 v1 = *(const f32x4*)(xr + 4);
    half8_t h;
    h[0] = (__fp16)v0[0]; h[1] = (__fp16)v0[1]; h[2] = (__fp16)v0[2]; h[3] = (__fp16)v0[3];
    h[4] = (__fp16)v1[0]; h[5] = (__fp16)v1[1]; h[6] = (__fp16)v1[2]; h[7] = (__fp16)v1[3];
    *(half8_t*)xhr = h;

    float s = 0.0f;
    #pragma unroll
    for (int i = 0; i < 8; ++i) s += (float)h[i];

    #pragma unroll
    for (int off = 32; off > 0; off >>= 1) s += __shfl_down(s, off, 64);
    __shared__ float red[4];
    const int lane = threadIdx.x & 63;
    const int w = threadIdx.x >> 6;
    if (lane == 0) red[w] = s;
    __syncthreads();
    if (threadIdx.x == 0) rowsum_part[t * 4 + q] = red[0] + red[1] + red[2] + red[3];
}

// ---------------------------------------------------------------------------
// Kernel 2: y[t,c] for c in a 32-channel band, FULL K per block (no K-split).
// qweight staged global->LDS in 1 KB-per-row bursts (HBM page friendly),
// double-buffered, 16B-chunk XOR swizzle (linear LDS dest + inverse-swizzled
// global source + swizzled ds_read). 8 waves: wave = (token quarter, channel half).
__global__ __launch_bounds__(512, 1) void woq_gemm_kernel(
        const int* __restrict__ qw, const __fp16* __restrict__ xh,
        const float* __restrict__ rowsum_part, const float* __restrict__ scales,
        const int* __restrict__ zps, const float* __restrict__ bias,
        float* __restrict__ out) {
    __shared__ int ldsB[2][BN * BK];   // 2 x 32 KB

    const int bx = blockIdx.x;         // 0..255 channel band
    const int cbase = bx * BN;
    const int tid = threadIdx.x;
    const int w = __builtin_amdgcn_readfirstlane(tid >> 6);   // wave 0..7
    const int lane = tid & 63;
    const int r = lane & 15;
    const int g = lane >> 4;
    const int wn = w >> 2;             // channel half (16 ch)
    const int wm = w & 3;              // token quarter (16 tokens)

    // A: token row (wm*16 + r), 16B per lane at k-offset g*8
    const __fp16* aptr = xh + (size_t)(wm * 16 + r) * K_DIM + g * 8;
    const int ldsrow = wn * 16 + r;    // B row this lane reads (0..31)
    const int sw = ldsrow & 7;         // read-side swizzle

    f32x4 acc = {0.f, 0.f, 0.f, 0.f};

    // Stage tile kt into ldsB[buf]: wave w stages rows [w*4, w*4+4), one
    // 1 KB global_load_lds per row. Global 16B-chunk index = lane ^ (row&7)
    // (inverse of the read-side swizzle; linear LDS dest per HW rule).
#define STAGE(buf, kt) do {                                                       \
        _Pragma("unroll")                                                         \
        for (int i = 0; i < 4; ++i) {                                             \
            const int row = w * 4 + i;                                            \
            const int* src = qw + (size_t)(cbase + row) * K_DIM + (kt) * BK       \
                             + ((lane ^ (row & 7)) << 2);                         \
            int* dst = &ldsB[buf][row * BK];                                      \
            __builtin_amdgcn_global_load_lds(                                     \
                (const __attribute__((address_space(1))) void*)src,               \
                (__attribute__((address_space(3))) void*)dst, 16, 0, 0);          \
        }                                                                         \
    } while (0)

    // Compute tile kt from ldsB[buf]: 8 k-steps of 32.
#define COMPUTE(buf, kt) do {                                                     \
        _Pragma("unroll")                                                         \
        for (int ks = 0; ks < BK / 32; ++ks) {                                    \
            half8_t af = *(const half8_t*)(aptr + (size_t)(kt) * BK + ks * 32);   \
            const int c0 = ks * 8 + g * 2;                                        \
            i32x4 q0 = *(const i32x4*)&ldsB[buf][ldsrow * BK + (((c0)^sw) << 2)]; \
            i32x4 q1 = *(const i32x4*)&ldsB[buf][ldsrow * BK + (((c0+1)^sw)<<2)]; \
            union { half8_t h8; half2_t h2[4]; } u;                               \
            u.h2[0] = __builtin_amdgcn_cvt_pkrtz((float)q0[0], (float)q0[1]);     \
            u.h2[1] = __builtin_amdgcn_cvt_pkrtz((float)q0[2], (float)q0[3]);     \
            u.h2[2] = __builtin_amdgcn_cvt_pkrtz((float)q1[0], (float)q1[1]);     \
            u.h2[3] = __builtin_amdgcn_cvt_pkrtz((float)q1[2], (float)q1[3]);     \
            acc = __builtin_amdgcn_mfma_f32_16x16x32_f16(af, u.h8, acc, 0, 0, 0); \
        }                                                                         \
    } while (0)

    STAGE(0, 0);
    __syncthreads();
    for (int kt = 0; kt < NT; ++kt) {
        if (kt + 1 < NT) STAGE((kt + 1) & 1, kt + 1);
        COMPUTE(kt & 1, kt);
        __syncthreads();   // drains vmcnt (stage kt+1 landed) + protects buf reuse
    }

    // Epilogue: y = sc*(S - zp*rowsum_t) + bias. D layout: row=g*4+j, col=r.
    const int c = cbase + wn * 16 + r;
    const float sc = scales[c];
    const float zp = (float)zps[c];
    const float bv = bias[c];
    #pragma unroll
    for (int j = 0; j < 4; ++j) {
        const int t = wm * 16 + g * 4 + j;
        const float rs = rowsum_part[t * 4 + 0] + rowsum_part[t * 4 + 1] +
                         rowsum_part[t * 4 + 2] + rowsum_part[t * 4 + 3];
        out[(size_t)t * N_DIM + c] = sc * (acc[j] - zp * rs) + bv;
    }
}

// ---------------------------------------------------------------------------
extern "C" void kernel_launch(void* const* d_in, const int* in_sizes, int n_in,
                              void* d_out, int out_size, void* d_ws, size_t ws_size,
                              hipStream_t stream) {
    const float* x      = (const float*)d_in[0];
    const int*   qw     = (const int*)d_in[1];
    const float* scales = (const float*)d_in[2];
    const int*   zps    = (const int*)d_in[3];
    const float* bias   = (const float*)d_in[4];
    float* out = (float*)d_out;

    // Workspace: xh (1 MiB @0) | rowsum_part (1 KiB @1 MiB)
    __fp16* xh          = (__fp16*)d_ws;
    float*  rowsum_part = (float*)((char*)d_ws + (1u << 20));

    prep_kernel<<<256, 256, 0, stream>>>(x, xh, rowsum_part);
    woq_gemm_kernel<<<NBLK, 512, 0, stream>>>(qw, xh, rowsum_part,
                                              scales, zps, bias, out);
}